// Round 9
// baseline (10934.325 us; speedup 1.0000x reference)
//
#include <hip/hip_runtime.h>

#define H      51
#define T_IN   512
#define T_TOT  576

// LDS floats: Whh1 (204 rows x 52) | Wih3 gates g,o (102 rows x 52) | exchange
#define W1_OFF 0
#define W3_OFF (204*52)
#define EX_OFF (W3_OFF + 102*52)      // 15,912
#define EX_F4  (2*4*52)               // one region: [2 elem][4 wave][52] float4 = 416
#define LDSFL  (EX_OFF + 2*EX_F4*4)   // 19,240 floats = 76,960 B -> 2 blocks/CU

__device__ __forceinline__ float bf2f(unsigned short u){return __uint_as_float(((unsigned)u)<<16);}
__device__ __forceinline__ unsigned short f2bf(float f){unsigned u=__float_as_uint(f);u+=0x7fffu+((u>>16)&1u);return (unsigned short)(u>>16);}
__device__ __forceinline__ float wget(const void* p,int i,bool is16){return is16?bf2f(((const unsigned short*)p)[i]):((const float*)p)[i];}
__device__ __forceinline__ float rl(float v,int k){
    return __uint_as_float((unsigned)__builtin_amdgcn_readlane((int)__float_as_uint(v),k));
}
__device__ __forceinline__ float sigm(float x){x=fminf(fmaxf(x,-30.f),30.f);return 1.f/(1.f+__expf(-x));}
__device__ __forceinline__ float tanh_f(float x){x=fminf(fmaxf(x,-15.f),15.f);float e=__expf(2.f*x);return (e-1.f)/(e+1.f);}
__device__ __forceinline__ float f4e(float4 v,int i){return i==0?v.x:i==1?v.y:i==2?v.z:v.w;}
__device__ __forceinline__ bool sniff16(const void* w){
    bool is16=true;
    const unsigned short* p=(const unsigned short*)w;
    for(int i=0;i<204;++i){ float v=fabsf(bf2f(p[i])); if(!(v<0.2f)) is16=false; }
    return is16;
}

#define L13(M) M(0) M(1) M(2) M(3) M(4) M(5) M(6) M(7) M(8) M(9) M(10) M(11) M(12)
#define DECL13(p) float p##_0,p##_1,p##_2,p##_3,p##_4,p##_5,p##_6,p##_7,p##_8,p##_9,p##_10,p##_11,p##_12;

#define AGW(dst,val) asm volatile("v_accvgpr_write_b32 %0, %1":"=a"(dst):"v"(val));
#define AR(s,d)      asm volatile("v_accvgpr_read_b32 %0, %1":"=v"(d):"a"(s));

#define RED(sv) { sv += __shfl_xor(sv,32,64); sv += __shfl_xor(sv,16,64); \
    sv += __shfl_xor(sv,8,64); sv += __shfl_xor(sv,4,64); \
    sv += __shfl_xor(sv,2,64); sv += __shfl_xor(sv,1,64); }

// K-split persistent LSTM, minimal per-wave stream:
//  512 blocks x 4 waves, block = 2 batch elements. Wave w owns k-slice [13w,13w+13)
//  of the REGISTER matrices (Wih2,Whh2,Whh3 in 156 asm-AGPRs; Wih3 i,f in 26 VGPRs)
//  and aligned slice {0,16,28,40}+{16,12,12,12} of the LDS matrices (Whh1, Wih3 g,o).
//  3 barriers/step: per layer all waves exchange 4-gate partials, every wave reduces
//  redundantly (fixed order -> bit-identical h everywhere). 2 exchange regions with
//  per-step parity alternation (race-free). <=256 unified regs/wave + 76,960 B LDS
//  -> 2 blocks/CU.
extern "C" __global__ void __launch_bounds__(256, 2)
lstm3_kernel(const void* g_in,  const void* g_Wih1, const void* g_Whh1,
             const void* g_bih1, const void* g_bhh1,
             const void* g_Wih2, const void* g_Whh2, const void* g_bih2, const void* g_bhh2,
             const void* g_Wih3, const void* g_Whh3, const void* g_bih3, const void* g_bhh3,
             const void* g_Wlin, const void* g_blin, void* g_out)
{
    extern __shared__ float smem[];

    const int tid  = threadIdx.x;
    const int lane = tid & 63;
    const int wid  = tid >> 6;
    const int eb   = blockIdx.x * 2;
    const int jeff = (lane < H) ? lane : (H - 1);
    const int KB   = 13 * wid;                                   // register k-slice base
    const int kstL = (wid==0)?0:(wid==1)?16:(wid==2)?28:40;      // LDS k-slice (b128-aligned)
    const int nbL  = (wid==0)?4:3;

    bool is16 = sniff16(g_Wih1);

    // ---- LDS staging: Whh1 rows 0..203, then Wih3 rows 2H..4H-1 (gates g,o)
    for (int i = tid; i < 204*52; i += 256) {
        int r = i/52, k = i - r*52;
        smem[W1_OFF + i] = (k < H) ? wget(g_Whh1, r*H + k, is16) : 0.f;
    }
    for (int i = tid; i < 102*52; i += 256) {
        int r = i/52, k = i - r*52;
        smem[W3_OFF + i] = (k < H) ? wget(g_Wih3, (2*H + r)*H + k, is16) : 0.f;
    }
    __syncthreads();

#define WCR(srcp,row,kk) (((KB+(kk)) < H) ? wget(srcp,(row)*H + KB + (kk), is16) : 0.f)

    // ---- AGPR weights: Wih2, Whh2, Whh3 (12 sets x 13 = 156)
    DECL13(wi2g0) DECL13(wi2g1) DECL13(wi2g2) DECL13(wi2g3)
    DECL13(wh2g0) DECL13(wh2g1) DECL13(wh2g2) DECL13(wh2g3)
    DECL13(wh3g0) DECL13(wh3g1) DECL13(wh3g2) DECL13(wh3g3)
#define AL(p,kk,srcp,row) { float t_ = WCR(srcp,row,kk); AGW(p##_##kk, t_) }
#define ALOAD13(p,srcp,row) AL(p,0,srcp,row) AL(p,1,srcp,row) AL(p,2,srcp,row) AL(p,3,srcp,row) \
    AL(p,4,srcp,row) AL(p,5,srcp,row) AL(p,6,srcp,row) AL(p,7,srcp,row) AL(p,8,srcp,row) \
    AL(p,9,srcp,row) AL(p,10,srcp,row) AL(p,11,srcp,row) AL(p,12,srcp,row)
    ALOAD13(wi2g0, g_Wih2, 0*H+jeff) ALOAD13(wi2g1, g_Wih2, 1*H+jeff)
    ALOAD13(wi2g2, g_Wih2, 2*H+jeff) ALOAD13(wi2g3, g_Wih2, 3*H+jeff)
    ALOAD13(wh2g0, g_Whh2, 0*H+jeff) ALOAD13(wh2g1, g_Whh2, 1*H+jeff)
    ALOAD13(wh2g2, g_Whh2, 2*H+jeff) ALOAD13(wh2g3, g_Whh2, 3*H+jeff)
    ALOAD13(wh3g0, g_Whh3, 0*H+jeff) ALOAD13(wh3g1, g_Whh3, 1*H+jeff)
    ALOAD13(wh3g2, g_Whh3, 2*H+jeff) ALOAD13(wh3g3, g_Whh3, 3*H+jeff)

    // ---- VGPR weights: Wih3 gates i,f (26)
    DECL13(wi3i) DECL13(wi3f)
#define VL(p,kk,srcp,row) p##_##kk = WCR(srcp,row,kk);
#define VLOAD13(p,srcp,row) VL(p,0,srcp,row) VL(p,1,srcp,row) VL(p,2,srcp,row) VL(p,3,srcp,row) \
    VL(p,4,srcp,row) VL(p,5,srcp,row) VL(p,6,srcp,row) VL(p,7,srcp,row) VL(p,8,srcp,row) \
    VL(p,9,srcp,row) VL(p,10,srcp,row) VL(p,11,srcp,row) VL(p,12,srcp,row)
    VLOAD13(wi3i, g_Wih3, 0*H+jeff)
    VLOAD13(wi3f, g_Wih3, 1*H+jeff)

    const float b1_0 = wget(g_bih1,0*H+jeff,is16)+wget(g_bhh1,0*H+jeff,is16);
    const float b1_1 = wget(g_bih1,1*H+jeff,is16)+wget(g_bhh1,1*H+jeff,is16);
    const float b1_2 = wget(g_bih1,2*H+jeff,is16)+wget(g_bhh1,2*H+jeff,is16);
    const float b1_3 = wget(g_bih1,3*H+jeff,is16)+wget(g_bhh1,3*H+jeff,is16);
    const float b2_0 = wget(g_bih2,0*H+jeff,is16)+wget(g_bhh2,0*H+jeff,is16);
    const float b2_1 = wget(g_bih2,1*H+jeff,is16)+wget(g_bhh2,1*H+jeff,is16);
    const float b2_2 = wget(g_bih2,2*H+jeff,is16)+wget(g_bhh2,2*H+jeff,is16);
    const float b2_3 = wget(g_bih2,3*H+jeff,is16)+wget(g_bhh2,3*H+jeff,is16);
    const float b3_0 = wget(g_bih3,0*H+jeff,is16)+wget(g_bhh3,0*H+jeff,is16);
    const float b3_1 = wget(g_bih3,1*H+jeff,is16)+wget(g_bhh3,1*H+jeff,is16);
    const float b3_2 = wget(g_bih3,2*H+jeff,is16)+wget(g_bhh3,2*H+jeff,is16);
    const float b3_3 = wget(g_bih3,3*H+jeff,is16)+wget(g_bhh3,3*H+jeff,is16);
    const float wi1_0 = wget(g_Wih1,0*H+jeff,is16);
    const float wi1_1 = wget(g_Wih1,1*H+jeff,is16);
    const float wi1_2 = wget(g_Wih1,2*H+jeff,is16);
    const float wi1_3 = wget(g_Wih1,3*H+jeff,is16);
    const float wlinr = (lane < H) ? wget(g_Wlin, lane, is16) : 0.f;
    const float blinr = wget(g_blin, 0, is16);

    const float4* A1_0 = (const float4*)(smem + W1_OFF + (0*H+jeff)*52 + kstL);
    const float4* A1_1 = (const float4*)(smem + W1_OFF + (1*H+jeff)*52 + kstL);
    const float4* A1_2 = (const float4*)(smem + W1_OFF + (2*H+jeff)*52 + kstL);
    const float4* A1_3 = (const float4*)(smem + W1_OFF + (3*H+jeff)*52 + kstL);
    const float4* A3g  = (const float4*)(smem + W3_OFF + (     jeff)*52 + kstL);
    const float4* A3o  = (const float4*)(smem + W3_OFF + (51 + jeff)*52 + kstL);
    float4* exb = (float4*)(smem + EX_OFF);

    float h1_0=0.f,h1_1=0.f,h2_0=0.f,h2_1=0.f,h3_0=0.f,h3_1=0.f;
    float c1_0=0.f,c1_1=0.f,c2_0=0.f,c2_1=0.f,c3_0=0.f,c3_1=0.f;
    float xf0=0.f,xf1=0.f;

    const unsigned short* in16 = (const unsigned short*)g_in;
    const float*          in32 = (const float*)g_in;
    unsigned short* o16w0 = (unsigned short*)g_out + (size_t)(eb+0)*T_TOT;
    unsigned short* o16w1 = (unsigned short*)g_out + (size_t)(eb+1)*T_TOT;
    float* o32w0 = (float*)g_out + (size_t)(eb+0)*T_TOT;
    float* o32w1 = (float*)g_out + (size_t)(eb+1)*T_TOT;

#define P2(kk) { int k_ = KB + (kk); \
    float s0_=rl(h1_0,k_), s1_=rl(h1_1,k_), r0_=rl(h2_0,k_), r1_=rl(h2_1,k_); \
    float w_; \
    AR(wi2g0_##kk,w_) a0_0=fmaf(w_,s0_,a0_0); a0_1=fmaf(w_,s1_,a0_1); \
    AR(wi2g1_##kk,w_) a1_0=fmaf(w_,s0_,a1_0); a1_1=fmaf(w_,s1_,a1_1); \
    AR(wi2g2_##kk,w_) a2_0=fmaf(w_,s0_,a2_0); a2_1=fmaf(w_,s1_,a2_1); \
    AR(wi2g3_##kk,w_) a3_0=fmaf(w_,s0_,a3_0); a3_1=fmaf(w_,s1_,a3_1); \
    AR(wh2g0_##kk,w_) a0_0=fmaf(w_,r0_,a0_0); a0_1=fmaf(w_,r1_,a0_1); \
    AR(wh2g1_##kk,w_) a1_0=fmaf(w_,r0_,a1_0); a1_1=fmaf(w_,r1_,a1_1); \
    AR(wh2g2_##kk,w_) a2_0=fmaf(w_,r0_,a2_0); a2_1=fmaf(w_,r1_,a2_1); \
    AR(wh2g3_##kk,w_) a3_0=fmaf(w_,r0_,a3_0); a3_1=fmaf(w_,r1_,a3_1); }

#define P3R(kk) { int k_ = KB + (kk); \
    float s0_=rl(h2_0,k_), s1_=rl(h2_1,k_), r0_=rl(h3_0,k_), r1_=rl(h3_1,k_); \
    a0_0=fmaf(wi3i_##kk,s0_,a0_0); a0_1=fmaf(wi3i_##kk,s1_,a0_1); \
    a1_0=fmaf(wi3f_##kk,s0_,a1_0); a1_1=fmaf(wi3f_##kk,s1_,a1_1); \
    float w_; \
    AR(wh3g0_##kk,w_) a0_0=fmaf(w_,r0_,a0_0); a0_1=fmaf(w_,r1_,a0_1); \
    AR(wh3g1_##kk,w_) a1_0=fmaf(w_,r0_,a1_0); a1_1=fmaf(w_,r1_,a1_1); \
    AR(wh3g2_##kk,w_) a2_0=fmaf(w_,r0_,a2_0); a2_1=fmaf(w_,r1_,a2_1); \
    AR(wh3g3_##kk,w_) a3_0=fmaf(w_,r0_,a3_0); a3_1=fmaf(w_,r1_,a3_1); }

#define UPD(q, cv, hv) { float ig_=sigm(q.x), fg_=sigm(q.y), gg_=tanh_f(q.z), og_=sigm(q.w); \
    cv = fg_*cv + ig_*gg_; hv = og_*tanh_f(cv); }

    // write partials, 1 barrier, every wave reduces redundantly (fixed order)
#define EXCH(ebr, c0v,h0v, c1v,h1v) { \
    if (lane < H) { \
        ebr[(0*4+wid)*52 + lane] = make_float4(a0_0,a1_0,a2_0,a3_0); \
        ebr[(1*4+wid)*52 + lane] = make_float4(a0_1,a1_1,a2_1,a3_1); \
    } \
    __syncthreads(); \
    { float4 q_ = ebr[0*52+jeff], t_; \
      t_ = ebr[1*52+jeff]; q_.x+=t_.x; q_.y+=t_.y; q_.z+=t_.z; q_.w+=t_.w; \
      t_ = ebr[2*52+jeff]; q_.x+=t_.x; q_.y+=t_.y; q_.z+=t_.z; q_.w+=t_.w; \
      t_ = ebr[3*52+jeff]; q_.x+=t_.x; q_.y+=t_.y; q_.z+=t_.z; q_.w+=t_.w; \
      UPD(q_, c0v, h0v) } \
    { float4 q_ = ebr[4*52+jeff], t_; \
      t_ = ebr[5*52+jeff]; q_.x+=t_.x; q_.y+=t_.y; q_.z+=t_.z; q_.w+=t_.w; \
      t_ = ebr[6*52+jeff]; q_.x+=t_.x; q_.y+=t_.y; q_.z+=t_.z; q_.w+=t_.w; \
      t_ = ebr[7*52+jeff]; q_.x+=t_.x; q_.y+=t_.y; q_.z+=t_.z; q_.w+=t_.w; \
      UPD(q_, c1v, h1v) } }

#pragma clang loop unroll(disable)
    for (int t = 0; t < T_TOT; ++t) {
        float4* ebA = exb + ((t & 1) ? EX_F4 : 0);
        float4* ebB = exb + ((t & 1) ? 0 : EX_F4);
        float a0_0,a1_0,a2_0,a3_0,a0_1,a1_1,a2_1,a3_1;

        // x loads issued first (consumed after the L1 matvec -> latency hidden)
        float x0 = xf0, x1 = xf1;
        if (wid == 3 && t < T_IN) {
            if (is16) { x0 = bf2f(in16[(size_t)(eb+0)*T_IN + t]);
                        x1 = bf2f(in16[(size_t)(eb+1)*T_IN + t]); }
            else      { x0 = in32[(size_t)(eb+0)*T_IN + t];
                        x1 = in32[(size_t)(eb+1)*T_IN + t]; }
        }

        // ---------------- layer 1: Whh1 . h1_old (LDS slice) ----------------
        a0_0=a1_0=a2_0=a3_0=a0_1=a1_1=a2_1=a3_1=0.f;
        for (int b = 0; b < nbL; ++b) {
            float4 u0=A1_0[b], u1=A1_1[b], u2=A1_2[b], u3=A1_3[b];
            int k0 = kstL + 4*b;
#pragma unroll
            for (int i = 0; i < 4; ++i) {
                float s0_=rl(h1_0,k0+i), s1_=rl(h1_1,k0+i);
                float w0=f4e(u0,i), w1=f4e(u1,i), w2=f4e(u2,i), w3=f4e(u3,i);
                a0_0=fmaf(w0,s0_,a0_0); a0_1=fmaf(w0,s1_,a0_1);
                a1_0=fmaf(w1,s0_,a1_0); a1_1=fmaf(w1,s1_,a1_1);
                a2_0=fmaf(w2,s0_,a2_0); a2_1=fmaf(w2,s1_,a2_1);
                a3_0=fmaf(w3,s0_,a3_0); a3_1=fmaf(w3,s1_,a3_1);
            }
        }
        if (wid == 3) {   // bias + input term folded into wave 3's partial
            a0_0 += fmaf(wi1_0,x0,b1_0); a0_1 += fmaf(wi1_0,x1,b1_0);
            a1_0 += fmaf(wi1_1,x0,b1_1); a1_1 += fmaf(wi1_1,x1,b1_1);
            a2_0 += fmaf(wi1_2,x0,b1_2); a2_1 += fmaf(wi1_2,x1,b1_2);
            a3_0 += fmaf(wi1_3,x0,b1_3); a3_1 += fmaf(wi1_3,x1,b1_3);
        }
        EXCH(ebA, c1_0,h1_0, c1_1,h1_1)

        // ---------------- layer 2: Wih2.h1 + Whh2.h2 (registers) ----------------
        if (wid == 3) { a0_0=a0_1=b2_0; a1_0=a1_1=b2_1; a2_0=a2_1=b2_2; a3_0=a3_1=b2_3; }
        else          { a0_0=a1_0=a2_0=a3_0=a0_1=a1_1=a2_1=a3_1=0.f; }
        L13(P2)
        EXCH(ebB, c2_0,h2_0, c2_1,h2_1)

        // ---------------- layer 3: Wih3{i,f} + Whh3 (regs) + Wih3{g,o} (LDS) ----------------
        if (wid == 3) { a0_0=a0_1=b3_0; a1_0=a1_1=b3_1; a2_0=a2_1=b3_2; a3_0=a3_1=b3_3; }
        else          { a0_0=a1_0=a2_0=a3_0=a0_1=a1_1=a2_1=a3_1=0.f; }
        L13(P3R)
        for (int b = 0; b < nbL; ++b) {
            float4 ug=A3g[b], uo=A3o[b];
            int k0 = kstL + 4*b;
#pragma unroll
            for (int i = 0; i < 4; ++i) {
                float s0_=rl(h2_0,k0+i), s1_=rl(h2_1,k0+i);
                float wg=f4e(ug,i), wo=f4e(uo,i);
                a2_0=fmaf(wg,s0_,a2_0); a2_1=fmaf(wg,s1_,a2_1);
                a3_0=fmaf(wo,s0_,a3_0); a3_1=fmaf(wo,s1_,a3_1);
            }
        }
        EXCH(ebA, c3_0,h3_0, c3_1,h3_1)

        // ---------------- head (redundant everywhere -> xf consistent) ----------------
        float s0 = wlinr * h3_0; RED(s0) float ov0 = s0 + blinr;
        float s1 = wlinr * h3_1; RED(s1) float ov1 = s1 + blinr;
        xf0 = ov0; xf1 = ov1;
        if (wid == 0 && lane == 0) {
            if (is16) { o16w0[t] = f2bf(ov0); o16w1[t] = f2bf(ov1); }
            else      { o32w0[t] = ov0;       o32w1[t] = ov1; }
        }
    }
}

extern "C" void kernel_launch(void* const* d_in, const int* in_sizes, int n_in,
                              void* d_out, int out_size, void* d_ws, size_t ws_size,
                              hipStream_t stream) {
    (void)in_sizes; (void)n_in; (void)d_ws; (void)ws_size; (void)out_size;
    size_t shmem = LDSFL * sizeof(float);   // 76,960 B -> 2 blocks/CU
    hipFuncSetAttribute((const void*)lstm3_kernel,
                        hipFuncAttributeMaxDynamicSharedMemorySize, (int)shmem);
    lstm3_kernel<<<dim3(512), dim3(256), shmem, stream>>>(
        d_in[0],  d_in[1],  d_in[2],  d_in[3],  d_in[4],
        d_in[5],  d_in[6],  d_in[7],  d_in[8],
        d_in[9],  d_in[10], d_in[11], d_in[12],
        d_in[13], d_in[14], d_out);
}